// Round 11
// baseline (16.916 us; speedup 1.0000x reference)
//
#include <hip/hip_runtime.h>
#include <hip/hip_bf16.h>
#include <cstdint>
#include <climits>

#define HW 112
#define NPIX (HW*HW)   // 12544
#define NB 2
#define NC 4
#define CHUNKS 14                  // chunks per (pair,dir); 8 rows each
#define HD_GRID (12*CHUNKS)        // 168

// Best-known structure (R7): 3 thin dependent nodes, no device-scope
// atomics/fences anywhere (R2/R8/R9/R10 proved every fusion variant is
// net-negative on this harness: a node costs ~1.5-2us, every in-kernel
// completion mechanism costs >= that).
// ws layout:
//   +0:      packed masks  uint64_t[12 masks][112 rows][2 words]   (21504 B)
//   +21504:  g^2 planes    uint16_t[12 planes][12544]              (301056 B)
//   +322560: partials      float2[168]  (sum, count) per hd block
// mask id = b*6 + m, m=0..2 -> A(j=m+1) (argmax==j), m=3..5 -> B(j=m-2) (label==1)

__global__ __launch_bounds__(128) void prep_kernel(
    const float* __restrict__ pred, const int* __restrict__ labels,
    unsigned long long* __restrict__ masks, unsigned short* __restrict__ gsqbuf)
{
  int blk = blockIdx.x;
  int b = blk / HW, r = blk % HW;
  int tid = threadIdx.x;
  int lane = tid & 63, wave = tid >> 6;
  int c = tid;

  int cls = 255;
  if (c < HW) {
    const float* p0 = pred + ((size_t)(b*NC)*HW + r)*HW + c;
    float best = p0[0]; cls = 0;
    #pragma unroll
    for (int ch = 1; ch < NC; ch++) {
      float v = p0[(size_t)ch*NPIX];
      if (v > best) { best = v; cls = ch; }   // strict > : argmax tie-break
    }
  }

  __shared__ unsigned long long sm[6][2];
  #pragma unroll
  for (int m = 0; m < 3; m++) {
    bool p = (c < HW) && (cls == m + 1);
    unsigned long long bal = __ballot(p);
    if (lane == 0) sm[m][wave] = bal;
  }
  #pragma unroll
  for (int m = 0; m < 3; m++) {
    int lab = (c < HW) ? labels[((size_t)(b*NC + (m+1))*HW + r)*HW + c] : 0;
    bool p = (c < HW) && (lab == 1);
    unsigned long long bal = __ballot(p);
    if (lane == 0) sm[3 + m][wave] = bal;
  }
  __syncthreads();

  if (tid < 12) {
    int m = tid >> 1, w = tid & 1;
    masks[((size_t)(b*6 + m)*HW + r)*2 + w] = sm[m][w];
  }

  // phase 1: horizontal nearest-set-pixel distance, O(1)/pixel via clz/ffs
  for (int item = tid; item < 6*HW; item += 128) {
    int m = item / HW, cc = item % HW;
    unsigned long long lo = sm[m][0], hi = sm[m][1];
    int left, right;
    if (cc < 64) {
      unsigned long long wl = lo & ((2ull << cc) - 1);
      left = wl ? 63 - __clzll(wl) : -1000;
      unsigned long long wr = lo & ~((1ull << cc) - 1);
      right = wr ? __ffsll(wr) - 1 : (hi ? 64 + __ffsll(hi) - 1 : 1000);
    } else {
      int cl = cc - 64;
      unsigned long long wl = hi & ((2ull << cl) - 1);
      left = wl ? 64 + 63 - __clzll(wl) : (lo ? 63 - __clzll(lo) : -1000);
      unsigned long long wr = hi & ~((1ull << cl) - 1);
      right = wr ? 64 + __ffsll(wr) - 1 : 1000;
    }
    int gv = min(min(cc - left, right - cc), 255);  // 255 sentinel: empty row
    gsqbuf[(size_t)(b*6 + m)*NPIX + r*HW + cc] = (unsigned short)(gv*gv);
  }
}

__device__ __forceinline__ int g2row(const unsigned short* __restrict__ g2p, int row) {
  return (row >= 0 && row < HW) ? (int)g2p[(size_t)row*HW] : 0x7fff;
}

// 168 thin blocks (pd x 8-row chunk, 128 threads = columns). Sliding 5-row
// register window, branch-free d<=2 candidates + rare exact tail (correct
// branch-and-bound: stop when d^2 >= best). One plain float2 store per block.
__global__ __launch_bounds__(128) void hd_kernel(
    const unsigned long long* __restrict__ masks,
    const unsigned short* __restrict__ gsqbuf,
    float2* __restrict__ partial)
{
  int blk = blockIdx.x;
  int pd = blk / CHUNKS, chunk = blk % CHUNKS;
  int b = pd / 6, k = pd % 6;
  // k<3: fwd for j=k+1 (src plane = B mask, target = A mask); k>=3 swapped
  int src = b*6 + (k + 3) % 6;
  int tid = threadIdx.x, lane = tid & 63, wv = tid >> 6;
  int c = tid;
  int rbase = chunk * 8;

  float sum = 0.f, cf = 0.f;
  if (c < HW) {
    const unsigned short* g2p = gsqbuf + (size_t)src*NPIX + c;
    int vm2 = g2row(g2p, rbase - 2), vm1 = g2row(g2p, rbase - 1);
    int v0  = g2row(g2p, rbase),     vp1 = g2row(g2p, rbase + 1);
    int vp2 = g2row(g2p, rbase + 2);
    #pragma unroll 8
    for (int i = 0; i < 8; i++) {
      int r = rbase + i;
      int best = v0;
      best = min(best, 1 + min(vm1, vp1));
      best = min(best, 4 + min(vm2, vp2));
      if (best > 9) {                         // rare exact tail
        for (int d = 3; d < HW; d++) {
          int dd = d*d;
          if (dd >= best) break;
          int ru = r - d, rd = r + d;
          if (ru >= 0)  best = min(best, dd + (int)g2p[(size_t)ru*HW]);
          if (rd < HW)  best = min(best, dd + (int)g2p[(size_t)rd*HW]);
        }
      }
      unsigned long long wm = masks[((size_t)pd*HW + r)*2 + (c >> 6)];
      if ((wm >> (c & 63)) & 1ull) { sum += sqrtf((float)best); cf += 1.f; }
      vm2 = vm1; vm1 = v0; v0 = vp1; vp1 = vp2; vp2 = g2row(g2p, r + 3);
    }
  }

  #pragma unroll
  for (int off = 32; off; off >>= 1) {
    sum += __shfl_down(sum, off, 64);
    cf  += __shfl_down(cf, off, 64);
  }
  __shared__ float red[4];
  if (lane == 0) { red[wv*2] = sum; red[wv*2 + 1] = cf; }
  __syncthreads();
  if (tid == 0) partial[blk] = make_float2(red[0] + red[2], red[1] + red[3]);
}

// 12 waves, one per (b,dir,class): deterministic shuffle-reduce of 14
// partials each, then thread 0 finalizes the 18 outputs.
__global__ __launch_bounds__(768) void fin_kernel(
    const float2* __restrict__ partial, float* __restrict__ out)
{
  int tid = threadIdx.x;
  int w = tid >> 6, lane = tid & 63;
  __shared__ float sacc[24];

  float s = 0.f, cnt = 0.f;
  if (lane < CHUNKS) {
    float2 p = partial[w*CHUNKS + lane];
    s = p.x; cnt = p.y;
  }
  #pragma unroll
  for (int off = 32; off; off >>= 1) {
    s   += __shfl_down(s, off, 64);
    cnt += __shfl_down(cnt, off, 64);
  }
  if (lane == 0) { sacc[w] = s; sacc[12 + w] = cnt; }
  __syncthreads();

  if (tid == 0) {
    float mhd[6], fhd[6], rhd[6];
    for (int i = 0; i < 6; i++) { mhd[i] = 0.f; fhd[i] = 0.f; rhd[i] = 0.f; }
    for (int bb = 0; bb < 2; bb++)
      for (int j = 1; j < 4; j++) {
        int pf = bb*6 + (j - 1);
        int pr = bb*6 + 3 + (j - 1);
        float fwd = sacc[pf] / sacc[12 + pf];
        float rev = sacc[pr] / sacc[12 + pr];
        fhd[j] += fwd; rhd[j] += rev; mhd[j] += fmaxf(fwd, rev);
      }
    float* arrs[3] = { mhd, fhd, rhd };
    for (int a = 0; a < 3; a++) {
      float* x = arrs[a];
      for (int i = 0; i < 4; i++) x[i] *= 0.5f;          // /N
      x[4] = (x[0] + x[1] + x[2] + x[3]) * 0.25f;        // mean(x[:C])
      x[5] = (x[1] + x[2] + x[3]) * (1.f / 3.f);         // mean(x[1:C])
      for (int i = 0; i < 6; i++) out[a*6 + i] = x[i];
    }
  }
}

extern "C" void kernel_launch(void* const* d_in, const int* in_sizes, int n_in,
                              void* d_out, int out_size, void* d_ws, size_t ws_size,
                              hipStream_t stream) {
  const float* pred = (const float*)d_in[0];
  const int* labels = (const int*)d_in[1];
  float* out = (float*)d_out;

  unsigned long long* masks = (unsigned long long*)d_ws;
  unsigned short* gsqbuf = (unsigned short*)((char*)d_ws + 21504);
  float2* partial = (float2*)((char*)d_ws + 322560);

  prep_kernel<<<NB*HW, 128, 0, stream>>>(pred, labels, masks, gsqbuf);
  hd_kernel<<<HD_GRID, 128, 0, stream>>>(masks, gsqbuf, partial);
  fin_kernel<<<1, 768, 0, stream>>>(partial, out);
}

// Round 12
// 15.009 us; speedup vs baseline: 1.1271x; 1.1271x over previous
//
#include <hip/hip_runtime.h>
#include <hip/hip_bf16.h>
#include <cstdint>
#include <climits>

#define HW 112
#define NPIX (HW*HW)   // 12544
#define NB 2
#define NC 4
#define CHUNKS 28                  // chunks per (pair,dir); 4 rows each
#define HD_GRID (12*CHUNKS)        // 336

// Best-measured kernel (R7, 14.8us): 3 thin dependent nodes, no device-scope
// atomics/fences. Fusion variants all regressed (R2/R5/R6/R8/R9/R10): a graph
// node costs ~1.5-2us here, and every in-kernel completion mechanism (fence,
// counter chain, spin block, fat-block concentration) costs at least that.
// ws layout:
//   +0:       packed masks  uint64_t[12 masks][112 rows][2 words]   (21504 B)
//   +21504:   g^2 planes    uint16_t[12 planes][12544]              (301056 B)
//   +322560:  partials      float2[336]  (sum, count) per hd block
// mask id = b*6 + m, m=0..2 -> A(j=m+1) (argmax==j), m=3..5 -> B(j=m-2) (label==1)

__global__ __launch_bounds__(128) void prep_kernel(
    const float* __restrict__ pred, const int* __restrict__ labels,
    unsigned long long* __restrict__ masks, unsigned short* __restrict__ gsqbuf)
{
  int blk = blockIdx.x;
  int b = blk / HW, r = blk % HW;
  int tid = threadIdx.x;
  int lane = tid & 63, wave = tid >> 6;
  int c = tid;

  int cls = 255;
  if (c < HW) {
    const float* p0 = pred + ((size_t)(b*NC)*HW + r)*HW + c;
    float best = p0[0]; cls = 0;
    #pragma unroll
    for (int ch = 1; ch < NC; ch++) {
      float v = p0[(size_t)ch*NPIX];
      if (v > best) { best = v; cls = ch; }   // strict > : first-index tie-break like argmax
    }
  }

  __shared__ unsigned long long sm[6][2];
  #pragma unroll
  for (int m = 0; m < 3; m++) {
    bool p = (c < HW) && (cls == m + 1);
    unsigned long long bal = __ballot(p);
    if (lane == 0) sm[m][wave] = bal;
  }
  #pragma unroll
  for (int m = 0; m < 3; m++) {
    int lab = (c < HW) ? labels[((size_t)(b*NC + (m+1))*HW + r)*HW + c] : 0;
    bool p = (c < HW) && (lab == 1);
    unsigned long long bal = __ballot(p);
    if (lane == 0) sm[3 + m][wave] = bal;
  }
  __syncthreads();

  if (tid < 12) {
    int m = tid >> 1, w = tid & 1;
    masks[((size_t)(b*6 + m)*HW + r)*2 + w] = sm[m][w];
  }

  // phase 1: horizontal nearest-set-pixel distance, O(1)/pixel via clz/ffs;
  // store g^2 as ushort
  for (int item = tid; item < 6*HW; item += 128) {
    int m = item / HW, cc = item % HW;
    unsigned long long lo = sm[m][0], hi = sm[m][1];
    int left, right;
    if (cc < 64) {
      unsigned long long wl = lo & ((2ull << cc) - 1);           // bits 0..cc
      left = wl ? 63 - __clzll(wl) : -1000;
      unsigned long long wr = lo & ~((1ull << cc) - 1);          // bits cc..63
      right = wr ? __ffsll(wr) - 1 : (hi ? 64 + __ffsll(hi) - 1 : 1000);
    } else {
      int cl = cc - 64;
      unsigned long long wl = hi & ((2ull << cl) - 1);           // bits 64..cc
      left = wl ? 64 + 63 - __clzll(wl) : (lo ? 63 - __clzll(lo) : -1000);
      unsigned long long wr = hi & ~((1ull << cl) - 1);          // bits cc..111
      right = wr ? 64 + __ffsll(wr) - 1 : 1000;
    }
    int gv = min(min(cc - left, right - cc), 255);  // 255 sentinel: empty row
    gsqbuf[(size_t)(b*6 + m)*NPIX + r*HW + cc] = (unsigned short)(gv*gv);
  }
}

// one block per (pair-dir, 4-row chunk), 128 threads (columns). Early-exit
// vertical scan: best = min over d of d^2 + g2[r+-d]; once d^2 >= best no
// farther row can win. d<=2 handled branch-free from an 8-row register
// window (independent coalesced loads, L1/L2-hit); rare tail loop for
// best > 9. Extra unconditional candidates are valid distances -> exact.
__global__ __launch_bounds__(128) void hd_kernel(
    const unsigned long long* __restrict__ masks,
    const unsigned short* __restrict__ gsqbuf,
    float2* __restrict__ partial)
{
  int blk = blockIdx.x;
  int pd = blk / CHUNKS, chunk = blk % CHUNKS;
  int b = pd / 6, k = pd % 6;
  // k<3: fwd for j=k+1 (src plane = B mask, target = A mask)
  // k>=3: rev for j=k-2 (src plane = A mask, target = B mask)
  int src = b*6 + (k + 3) % 6;
  int tid = threadIdx.x, lane = tid & 63, wv = tid >> 6;
  int c = tid;
  int r0 = chunk * 4;

  float sum = 0.f, cf = 0.f;
  if (c < HW) {
    const unsigned short* g2p = gsqbuf + (size_t)src*NPIX + c;

    // 8-row register window: rows r0-2 .. r0+5 (guarded), all independent loads
    int w[8];
    #pragma unroll
    for (int t = 0; t < 8; t++) {
      int gr = r0 - 2 + t;
      w[t] = (gr >= 0 && gr < HW) ? (int)g2p[(size_t)gr*HW] : 0x7fff;
    }

    #pragma unroll
    for (int i = 0; i < 4; i++) {
      int r = r0 + i;
      int best = w[i + 2];                                  // d=0
      best = min(best, 1 + min(w[i + 1], w[i + 3]));        // d=1
      best = min(best, 4 + min(w[i],     w[i + 4]));        // d=2
      if (best > 9) {                                       // rare tail
        for (int d = 3; d < HW; d++) {
          int dd = d*d;
          if (dd >= best) break;
          int ru = r - d, rd = r + d;
          if (ru >= 0)  best = min(best, dd + (int)g2p[(size_t)ru*HW]);
          if (rd < HW)  best = min(best, dd + (int)g2p[(size_t)rd*HW]);
        }
      }
      unsigned long long wm = masks[((size_t)pd*HW + r)*2 + (c >> 6)];
      if ((wm >> (c & 63)) & 1ull) { sum += sqrtf((float)best); cf += 1.f; }
    }
  }

  #pragma unroll
  for (int off = 32; off; off >>= 1) {
    sum += __shfl_down(sum, off, 64);
    cf  += __shfl_down(cf, off, 64);
  }
  __shared__ float red[4];
  if (lane == 0) { red[wv*2] = sum; red[wv*2 + 1] = cf; }
  __syncthreads();
  if (tid == 0) partial[blk] = make_float2(red[0] + red[2], red[1] + red[3]);
}

// 12 waves, one per (b,dir,class): deterministic shuffle-reduce of 28 partials,
// then thread 0 finalizes the 18 outputs.
__global__ __launch_bounds__(768) void fin_kernel(
    const float2* __restrict__ partial, float* __restrict__ out)
{
  int tid = threadIdx.x;
  int w = tid >> 6, lane = tid & 63;
  __shared__ float sacc[24];

  float s = 0.f, cnt = 0.f;
  if (lane < CHUNKS) {
    float2 p = partial[w*CHUNKS + lane];
    s = p.x; cnt = p.y;
  }
  #pragma unroll
  for (int off = 32; off; off >>= 1) {
    s   += __shfl_down(s, off, 64);
    cnt += __shfl_down(cnt, off, 64);
  }
  if (lane == 0) { sacc[w] = s; sacc[12 + w] = cnt; }
  __syncthreads();

  if (tid == 0) {
    float mhd[6], fhd[6], rhd[6];
    for (int i = 0; i < 6; i++) { mhd[i] = 0.f; fhd[i] = 0.f; rhd[i] = 0.f; }
    for (int bb = 0; bb < 2; bb++)
      for (int j = 1; j < 4; j++) {
        int pf = bb*6 + (j - 1);
        int pr = bb*6 + 3 + (j - 1);
        float fwd = sacc[pf] / sacc[12 + pf];
        float rev = sacc[pr] / sacc[12 + pr];
        fhd[j] += fwd; rhd[j] += rev; mhd[j] += fmaxf(fwd, rev);
      }
    float* arrs[3] = { mhd, fhd, rhd };
    for (int a = 0; a < 3; a++) {
      float* x = arrs[a];
      for (int i = 0; i < 4; i++) x[i] *= 0.5f;          // /N
      x[4] = (x[0] + x[1] + x[2] + x[3]) * 0.25f;        // mean(x[:C])
      x[5] = (x[1] + x[2] + x[3]) * (1.f / 3.f);         // mean(x[1:C])
      for (int i = 0; i < 6; i++) out[a*6 + i] = x[i];
    }
  }
}

extern "C" void kernel_launch(void* const* d_in, const int* in_sizes, int n_in,
                              void* d_out, int out_size, void* d_ws, size_t ws_size,
                              hipStream_t stream) {
  const float* pred = (const float*)d_in[0];
  const int* labels = (const int*)d_in[1];
  float* out = (float*)d_out;

  unsigned long long* masks = (unsigned long long*)d_ws;
  unsigned short* gsqbuf = (unsigned short*)((char*)d_ws + 21504);
  float2* partial = (float2*)((char*)d_ws + 21504 + (size_t)12*NPIX*sizeof(unsigned short));

  prep_kernel<<<NB*HW, 128, 0, stream>>>(pred, labels, masks, gsqbuf);
  hd_kernel<<<HD_GRID, 128, 0, stream>>>(masks, gsqbuf, partial);
  fin_kernel<<<1, 768, 0, stream>>>(partial, out);
}